// Round 1
// baseline (375.169 us; speedup 1.0000x reference)
//
#include <hip/hip_runtime.h>

// Problem: B=512, V=256, W=64, H=64. Outputs: x_tilde_seq (64,512,256) fp32, h_seq (64,512,64) fp32.

#define KLOG2E  1.4426950408889634f   // log2(e)
#define K2LOG2E 2.8853900817779268f   // 2*log2(e)

__device__ __forceinline__ float frcp(float x)  { return __builtin_amdgcn_rcpf(x); }
__device__ __forceinline__ float fexp2(float x) { return __builtin_amdgcn_exp2f(x); }
__device__ __forceinline__ float fsigmoid(float x) { return frcp(1.f + fexp2(-KLOG2E * x)); }
__device__ __forceinline__ float ftanh(float x) { return 1.f - 2.f * frcp(fexp2(K2LOG2E * x) + 1.f); }

// LDS layout (float offsets)
#define L_E    0                   // E[256][68]  = exp(2*(u_out+b_u)), padded stride 68
#define L_WW   17408               // w_w rows [64][132] (row-major, padded)
#define L_PS   (17408 + 8448)      // partials [2048]
#define L_XT   (L_PS + 2048)       // x_tilde [256]
#define L_XS   (L_XT + 256)        // x_t stash [256]
#define L_EW   (L_XS + 256)        // e_w [64]
#define L_HC   (L_EW + 64)         // h||c [128]
#define L_BI   (L_HC + 128)        // b_ih+b_hh [256]
#define L_WV   (L_BI + 256)        // -2*w_v [64]
#define L_BW   (L_WV + 64)         // b_w [64]
#define L_TOT  (L_BW + 64)         // 28992 floats = 115968 bytes

__global__ __launch_bounds__(512, 2) void enc_kernel(
    const float* __restrict__ x,     // (512,256,64)
    const float* __restrict__ w_ih,  // (256,256)
    const float* __restrict__ w_hh,  // (256,64)
    const float* __restrict__ b_ih,  // (256)
    const float* __restrict__ b_hh,  // (256)
    const float* __restrict__ w_v,   // (64)
    const float* __restrict__ w_w,   // (64,128)
    const float* __restrict__ b_w,   // (64)
    const float* __restrict__ w_u,   // (64,64)
    const float* __restrict__ b_u,   // (64)
    float* __restrict__ out_xt,      // (64,512,256)
    float* __restrict__ out_h)       // (64,512,64)
{
    extern __shared__ float lds[];
    float* E    = lds + L_E;
    float* wwL  = lds + L_WW;
    float* ps   = lds + L_PS;
    float* xt   = lds + L_XT;
    float* xsL  = lds + L_XS;
    float* ew   = lds + L_EW;
    float* hc   = lds + L_HC;
    float* biasL= lds + L_BI;
    float* wv2  = lds + L_WV;
    float* bwL  = lds + L_BW;

    const int tid   = threadIdx.x;
    const int lanew = tid & 63;    // 0..63  (w index / jg)
    const int wavei = tid >> 6;    // 0..7   (kg / sg)
    const int j     = tid & 255;   // v index for score phase
    const int p     = tid >> 8;    // 0/1 half for score phase

    // ---- persistent per-thread gate weights: J=4 outputs x S=8 v-slices ----
    // thread (jg=lanew, sg=wavei): j_jj = jg + 64*jj ; v-slice [32*sg, 32*sg+32)
    float wihr[128];
    float whhr[32];
    {
        const int jg = lanew, sg = wavei;
#pragma unroll
        for (int jj = 0; jj < 4; ++jj) {
            const float4* g4 = (const float4*)(w_ih + (jg + 64*jj)*256 + sg*32);
#pragma unroll
            for (int i = 0; i < 8; ++i) {
                float4 v4 = g4[i];
                wihr[jj*32 + 4*i + 0] = v4.x; wihr[jj*32 + 4*i + 1] = v4.y;
                wihr[jj*32 + 4*i + 2] = v4.z; wihr[jj*32 + 4*i + 3] = v4.w;
            }
            const float4* h4 = (const float4*)(w_hh + (jg + 64*jj)*64 + sg*8);
#pragma unroll
            for (int i = 0; i < 2; ++i) {
                float4 v4 = h4[i];
                whhr[jj*8 + 4*i + 0] = v4.x; whhr[jj*8 + 4*i + 1] = v4.y;
                whhr[jj*8 + 4*i + 2] = v4.z; whhr[jj*8 + 4*i + 3] = v4.w;
            }
        }
    }

    // ---- one-time LDS fills ----
    if (tid < 256) biasL[tid] = b_ih[tid] + b_hh[tid];
    if (tid < 64) { wv2[tid] = -2.f * w_v[tid]; bwL[tid] = b_w[tid]; }
    for (int i = tid; i < 8192; i += 512) {           // w_w row-major padded
        int r = i >> 7, c = i & 127;
        wwL[r*132 + c] = w_w[i];
    }
    float Sv = 0.f;
#pragma unroll
    for (int wv = 0; wv < 64; ++wv) Sv += w_v[wv];    // uniform: s_loads
    const float bu_lane = b_u[lanew];
    __syncthreads();

    for (int bb = 0; bb < 2; ++bb) {
        const int b = blockIdx.x + (bb << 8);

        // ---- E = exp(2*(x[b] @ w_u^T + b_u)) into LDS, two half-dots ----
        // thread: w = lanew; wave handles v in [32*wavei, 32*wavei+32)
#pragma unroll 1
        for (int half = 0; half < 2; ++half) {
            float4 wu_r[8];
#pragma unroll
            for (int i = 0; i < 8; ++i)
                wu_r[i] = *(const float4*)&w_u[lanew*64 + half*32 + 4*i];
            const float* xb = x + b*16384 + half*32;
#pragma unroll 2
            for (int vi = 0; vi < 32; ++vi) {
                int v = __builtin_amdgcn_readfirstlane(wavei*32 + vi);
                const float4* xr = (const float4*)(xb + v*64);
                float acc = 0.f;
#pragma unroll
                for (int i = 0; i < 8; ++i) {
                    float4 xx = xr[i]; float4 wu = wu_r[i];
                    acc += xx.x*wu.x + xx.y*wu.y + xx.z*wu.z + xx.w*wu.w;
                }
                if (half == 0) {
                    E[v*68 + lanew] = acc + bu_lane;
                } else {
                    float u2 = E[v*68 + lanew] + acc;
                    E[v*68 + lanew] = fexp2(K2LOG2E * u2);
                }
            }
        }
        if (tid < 128) hc[tid] = 0.f;
        __syncthreads();

        float xnext = x[b*16384 + j*64];   // prefetch x_t for t=0

        for (int t = 0; t < 64; ++t) {
            // stash current x_t (written by p==0 threads)
            if (p == 0) xsL[j] = xnext;

            // ---- wout partials: thread (w=lanew, kg=wavei) ----
            {
                float acc = 0.f;
                const float4* hcw = (const float4*)(hc + wavei*16);
                const float4* ww4 = (const float4*)&wwL[lanew*132 + wavei*16];
#pragma unroll
                for (int i = 0; i < 4; ++i) {
                    float4 hv = hcw[i], wv = ww4[i];
                    acc += hv.x*wv.x + hv.y*wv.y + hv.z*wv.z + hv.w*wv.w;
                }
                ps[tid] = acc;
            }
            // prefetch next x_t (latency spans 3 barriers)
            {
                int tn = (t < 63) ? (t + 1) : 63;
                xnext = x[b*16384 + j*64 + tn];
            }
            __syncthreads();   // s1

            if (tid < 64) {
                float s = bwL[tid];
#pragma unroll
                for (int i = 0; i < 8; ++i) s += ps[tid + 64*i];
                ew[tid] = fexp2(K2LOG2E * s);   // e_w = exp(2*wout)
            }
            __syncthreads();   // s2

            // ---- score partials: thread (v=j, w-half=p) ----
            // tanh(wout+u) = 1 - 2/(E*e_w + 1);  partial = sum wv2*rcp(P+1)
            {
                float acc = 0.f;
                const float4* E4  = (const float4*)&E[j*68 + p*32];
                const float4* ew4 = (const float4*)&ew[p*32];
                const float4* wv4 = (const float4*)&wv2[p*32];
#pragma unroll
                for (int i = 0; i < 8; ++i) {
                    float4 e4 = E4[i], c4 = ew4[i], v4 = wv4[i];
                    acc += v4.x * frcp(e4.x*c4.x + 1.f);
                    acc += v4.y * frcp(e4.y*c4.y + 1.f);
                    acc += v4.z * frcp(e4.z*c4.z + 1.f);
                    acc += v4.w * frcp(e4.w*c4.w + 1.f);
                }
                ps[tid] = acc;
            }
            __syncthreads();   // s3

            // ---- softmax + x_tilde: wave 0 only (no max-subtract: |score|<=2.6) ----
            if (tid < 64) {
                float s0 = Sv + ps[tid      ] + ps[tid + 256];
                float s1 = Sv + ps[tid +  64] + ps[tid + 320];
                float s2 = Sv + ps[tid + 128] + ps[tid + 384];
                float s3 = Sv + ps[tid + 192] + ps[tid + 448];
                float e0 = fexp2(KLOG2E*s0), e1 = fexp2(KLOG2E*s1);
                float e2 = fexp2(KLOG2E*s2), e3 = fexp2(KLOG2E*s3);
                float sum = (e0 + e1) + (e2 + e3);
#pragma unroll
                for (int off = 32; off >= 1; off >>= 1)
                    sum += __shfl_xor(sum, off, 64);
                float r = frcp(sum);
                float t0 = e0*r*xsL[tid      ];
                float t1 = e1*r*xsL[tid +  64];
                float t2 = e2*r*xsL[tid + 128];
                float t3 = e3*r*xsL[tid + 192];
                xt[tid      ] = t0; xt[tid +  64] = t1;
                xt[tid + 128] = t2; xt[tid + 192] = t3;
                float* o = out_xt + t*131072 + b*256;
                o[tid      ] = t0; o[tid +  64] = t1;
                o[tid + 128] = t2; o[tid + 192] = t3;
            }
            __syncthreads();   // s4

            // ---- gates partials: thread (jg=lanew, sg=wavei), 4 outputs ----
            {
                const int jg = lanew, sg = wavei;
                float a0 = 0.f, a1 = 0.f, a2 = 0.f, a3 = 0.f;
                const float4* xt4 = (const float4*)(xt + sg*32);
#pragma unroll
                for (int i = 0; i < 8; ++i) {
                    float4 xv = xt4[i];
                    a0 += xv.x*wihr[  4*i] + xv.y*wihr[  4*i+1] + xv.z*wihr[  4*i+2] + xv.w*wihr[  4*i+3];
                    a1 += xv.x*wihr[32+4*i] + xv.y*wihr[32+4*i+1] + xv.z*wihr[32+4*i+2] + xv.w*wihr[32+4*i+3];
                    a2 += xv.x*wihr[64+4*i] + xv.y*wihr[64+4*i+1] + xv.z*wihr[64+4*i+2] + xv.w*wihr[64+4*i+3];
                    a3 += xv.x*wihr[96+4*i] + xv.y*wihr[96+4*i+1] + xv.z*wihr[96+4*i+2] + xv.w*wihr[96+4*i+3];
                }
                const float4* hc4 = (const float4*)(hc + sg*8);
#pragma unroll
                for (int i = 0; i < 2; ++i) {
                    float4 hv = hc4[i];
                    a0 += hv.x*whhr[  4*i] + hv.y*whhr[  4*i+1] + hv.z*whhr[  4*i+2] + hv.w*whhr[  4*i+3];
                    a1 += hv.x*whhr[8+4*i] + hv.y*whhr[8+4*i+1] + hv.z*whhr[8+4*i+2] + hv.w*whhr[8+4*i+3];
                    a2 += hv.x*whhr[16+4*i] + hv.y*whhr[16+4*i+1] + hv.z*whhr[16+4*i+2] + hv.w*whhr[16+4*i+3];
                    a3 += hv.x*whhr[24+4*i] + hv.y*whhr[24+4*i+1] + hv.z*whhr[24+4*i+2] + hv.w*whhr[24+4*i+3];
                }
                ps[sg*256 + jg      ] = a0;
                ps[sg*256 + jg +  64] = a1;
                ps[sg*256 + jg + 128] = a2;
                ps[sg*256 + jg + 192] = a3;
            }
            __syncthreads();   // s5

            // ---- gate combine + LSTM cell: wave 0 (k = tid) ----
            if (tid < 64) {
                const int k = tid;
                float gi = biasL[k], gf = biasL[64+k], gg = biasL[128+k], go = biasL[192+k];
#pragma unroll
                for (int s = 0; s < 8; ++s) {
                    gi += ps[s*256 + k      ];
                    gf += ps[s*256 + k +  64];
                    gg += ps[s*256 + k + 128];
                    go += ps[s*256 + k + 192];
                }
                gi = fsigmoid(gi); gf = fsigmoid(gf);
                gg = ftanh(gg);    go = fsigmoid(go);
                float cn = gf * hc[64 + k] + gi * gg;
                float hn = go * ftanh(cn);
                hc[k] = hn; hc[64 + k] = cn;
                out_h[t*32768 + b*64 + k] = hn;
            }
            __syncthreads();   // s6
        }
        __syncthreads();  // guard before next batch overwrites E
    }
}

extern "C" void kernel_launch(void* const* d_in, const int* in_sizes, int n_in,
                              void* d_out, int out_size, void* d_ws, size_t ws_size,
                              hipStream_t stream) {
    const float* x    = (const float*)d_in[0];
    const float* w_ih = (const float*)d_in[1];
    const float* w_hh = (const float*)d_in[2];
    const float* b_ih = (const float*)d_in[3];
    const float* b_hh = (const float*)d_in[4];
    const float* w_v  = (const float*)d_in[5];
    const float* w_w  = (const float*)d_in[6];
    const float* b_w  = (const float*)d_in[7];
    const float* w_u  = (const float*)d_in[8];
    const float* b_u  = (const float*)d_in[9];

    float* out_xt = (float*)d_out;
    float* out_h  = out_xt + 64*512*256;

    const size_t shbytes = (size_t)L_TOT * sizeof(float);  // 115968 B
    hipFuncSetAttribute((const void*)enc_kernel,
                        hipFuncAttributeMaxDynamicSharedMemorySize, (int)shbytes);
    enc_kernel<<<dim3(256), dim3(512), shbytes, stream>>>(
        x, w_ih, w_hh, b_ih, b_hh, w_v, w_w, b_w, w_u, b_u, out_xt, out_h);
}